// Round 3
// baseline (40.032 us; speedup 1.0000x reference)
//
#include <hip/hip_runtime.h>
#include <math.h>

// Problem constants
#define NB 8
#define NN 128
static constexpr float NEGV = -1000000.0f;

// Kernel 1: one workgroup per (b, r, e). 256 threads = 4 waves.
// lane l: soff = l>>5 (s parity), c4 = l&31 (float4 chunk of the 128-c slice)
// wave w handles s = 8*si + 2*w + soff, si = 0..15, held in registers.
// Writes partial aggregation (its e only) to ws: partial[e][b][r][h][c].
__global__ __launch_bounds__(256, 4)
void edge_attn_partial(const float* __restrict__ edge_msgs,
                       const float* __restrict__ node_states,
                       const float* __restrict__ W,
                       const float* __restrict__ bvec,
                       const int*   __restrict__ edges,
                       float* __restrict__ partial) {
    const int blk = blockIdx.x;
    const int e = blk & 1;
    const int r = (blk >> 1) & 127;
    const int b = blk >> 8;

    const int t    = threadIdx.x;
    const int w    = t >> 6;     // wave 0..3
    const int l    = t & 63;     // lane 0..63
    const int soff = l >> 5;     // 0/1
    const int c4   = l & 31;     // float4 chunk over 128 c

    __shared__ float sval[128 * 5];      // scores [s][h], stride 5 (bank-bijective)
    __shared__ float wts [128 * 5];      // softmax weights [s][h], stride 5
    __shared__ float ebias[128];         // mask bias for this e
    __shared__ float nodep[4];           // node projection per h
    __shared__ float outbuf[4][4][128];  // [wave][h][c]

    // ---- W_msg fragment for this lane's c-chunk
    float4 wm0 = *(const float4*)(W +   0 + c4 * 4);
    float4 wm1 = *(const float4*)(W + 256 + c4 * 4);
    float4 wm2 = *(const float4*)(W + 512 + c4 * 4);
    float4 wm3 = *(const float4*)(W + 768 + c4 * 4);

    // ---- node projection: wave 0 only, 64-lane reduce
    if (w == 0) {
        float2 nv  = *(const float2*)(node_states + ((size_t)b * NN + r) * 128 + l * 2);
        float2 wn0 = *(const float2*)(W + 128 + l * 2);
        float2 wn1 = *(const float2*)(W + 384 + l * 2);
        float2 wn2 = *(const float2*)(W + 640 + l * 2);
        float2 wn3 = *(const float2*)(W + 896 + l * 2);
        float np0 = nv.x * wn0.x + nv.y * wn0.y;
        float np1 = nv.x * wn1.x + nv.y * wn1.y;
        float np2 = nv.x * wn2.x + nv.y * wn2.y;
        float np3 = nv.x * wn3.x + nv.y * wn3.y;
        #pragma unroll
        for (int m = 32; m >= 1; m >>= 1) {
            np0 += __shfl_xor(np0, m);
            np1 += __shfl_xor(np1, m);
            np2 += __shfl_xor(np2, m);
            np3 += __shfl_xor(np3, m);
        }
        if (l == 0) { nodep[0] = np0; nodep[1] = np1; nodep[2] = np2; nodep[3] = np3; }
    }

    // ---- edge mask bias for this e: 128 threads load one int each (L2/L3-cached)
    if (t < 128) {
        int ev = edges[(((size_t)b * NN + t) * NN + r) * 3 + 1 + e];
        ebias[t] = (1.0f - (float)ev) * NEGV;
    }

    // ---- Stream this (b, r, e) column into registers (single HBM read)
    const float* bp = edge_msgs
        + (size_t)b * (NN * NN * 256)
        + (size_t)r * 256
        + e * 128 + c4 * 4;
    // stride per sender s: NN*2*128 = 32768 floats

    float4 v[16];
    #pragma unroll
    for (int si = 0; si < 16; ++si)
        v[si] = *(const float4*)(bp + (size_t)(8 * si + 2 * w + soff) * 32768);

    // ---- Pass A: scores. swap-select quad reduce (masks 1,2) then
    // xor 4,8,16 butterfly within the 32-lane half -> every lane holds
    // score(s, h=l&3); quad-0 lanes write to LDS.
    const int hsel = l & 3;
    const bool o1  = (l & 1) != 0;
    const bool o2  = (l & 2) != 0;
    #pragma unroll
    for (int si = 0; si < 16; ++si) {
        int s = 8 * si + 2 * w + soff;
        float p0 = v[si].x * wm0.x + v[si].y * wm0.y + v[si].z * wm0.z + v[si].w * wm0.w;
        float p1 = v[si].x * wm1.x + v[si].y * wm1.y + v[si].z * wm1.z + v[si].w * wm1.w;
        float p2 = v[si].x * wm2.x + v[si].y * wm2.y + v[si].z * wm2.z + v[si].w * wm2.w;
        float p3 = v[si].x * wm3.x + v[si].y * wm3.y + v[si].z * wm3.z + v[si].w * wm3.w;
        float x01 = o1 ? p1 : p0, y01 = o1 ? p0 : p1;
        float x23 = o1 ? p3 : p2, y23 = o1 ? p2 : p3;
        float r01 = x01 + __shfl_xor(y01, 1);
        float r23 = x23 + __shfl_xor(y23, 1);
        float x2 = o2 ? r23 : r01, y2 = o2 ? r01 : r23;
        float val = x2 + __shfl_xor(y2, 2);   // lane hsel holds quad sum for h=hsel
        val += __shfl_xor(val, 4);
        val += __shfl_xor(val, 8);
        val += __shfl_xor(val, 16);           // sum over all 8 quads in this half
        if ((l & 31) < 4)
            sval[s * 5 + hsel] = val;
    }
    __syncthreads();

    // ---- Softmax over s per h: 4 groups x 32 lanes (first 128 threads)
    if (t < 128) {
        int h = t >> 5;         // 0..3
        int j = t & 31;
        float bb = bvec[h] + nodep[h];
        float y0, y1, y2, y3;
        {
            float x;
            x = sval[(j +  0) * 5 + h] + bb; x = x > 0.f ? x : expm1f(x); y0 = x + ebias[j +  0];
            x = sval[(j + 32) * 5 + h] + bb; x = x > 0.f ? x : expm1f(x); y1 = x + ebias[j + 32];
            x = sval[(j + 64) * 5 + h] + bb; x = x > 0.f ? x : expm1f(x); y2 = x + ebias[j + 64];
            x = sval[(j + 96) * 5 + h] + bb; x = x > 0.f ? x : expm1f(x); y3 = x + ebias[j + 96];
        }
        float m4 = fmaxf(fmaxf(y0, y1), fmaxf(y2, y3));
        #pragma unroll
        for (int m = 16; m >= 1; m >>= 1) m4 = fmaxf(m4, __shfl_xor(m4, m));
        y0 = __expf(y0 - m4); y1 = __expf(y1 - m4);
        y2 = __expf(y2 - m4); y3 = __expf(y3 - m4);
        float sum = y0 + y1 + y2 + y3;
        #pragma unroll
        for (int m = 16; m >= 1; m >>= 1) sum += __shfl_xor(sum, m);
        float inv = 1.0f / sum;
        wts[(j +  0) * 5 + h] = y0 * inv;
        wts[(j + 32) * 5 + h] = y1 * inv;
        wts[(j + 64) * 5 + h] = y2 * inv;
        wts[(j + 96) * 5 + h] = y3 * inv;
    }
    __syncthreads();

    // ---- Pass B: weighted aggregation from register-resident tile
    float4 a0 = {0,0,0,0}, a1 = {0,0,0,0}, a2 = {0,0,0,0}, a3 = {0,0,0,0};
    #pragma unroll
    for (int si = 0; si < 16; ++si) {
        int s = 8 * si + 2 * w + soff;
        float w0 = wts[s * 5 + 0];   // same address across 32-lane half -> broadcast
        float w1 = wts[s * 5 + 1];
        float w2 = wts[s * 5 + 2];
        float w3 = wts[s * 5 + 3];
        a0.x += w0 * v[si].x; a0.y += w0 * v[si].y; a0.z += w0 * v[si].z; a0.w += w0 * v[si].w;
        a1.x += w1 * v[si].x; a1.y += w1 * v[si].y; a1.z += w1 * v[si].z; a1.w += w1 * v[si].w;
        a2.x += w2 * v[si].x; a2.y += w2 * v[si].y; a2.z += w2 * v[si].z; a2.w += w2 * v[si].w;
        a3.x += w3 * v[si].x; a3.y += w3 * v[si].y; a3.z += w3 * v[si].z; a3.w += w3 * v[si].w;
    }
    // fold s-parity halves: lane l and l^32 hold the same c4
    a0.x += __shfl_xor(a0.x, 32); a0.y += __shfl_xor(a0.y, 32); a0.z += __shfl_xor(a0.z, 32); a0.w += __shfl_xor(a0.w, 32);
    a1.x += __shfl_xor(a1.x, 32); a1.y += __shfl_xor(a1.y, 32); a1.z += __shfl_xor(a1.z, 32); a1.w += __shfl_xor(a1.w, 32);
    a2.x += __shfl_xor(a2.x, 32); a2.y += __shfl_xor(a2.y, 32); a2.z += __shfl_xor(a2.z, 32); a2.w += __shfl_xor(a2.w, 32);
    a3.x += __shfl_xor(a3.x, 32); a3.y += __shfl_xor(a3.y, 32); a3.z += __shfl_xor(a3.z, 32); a3.w += __shfl_xor(a3.w, 32);

    if (soff == 0) {
        *(float4*)&outbuf[w][0][c4 * 4] = a0;
        *(float4*)&outbuf[w][1][c4 * 4] = a1;
        *(float4*)&outbuf[w][2][c4 * 4] = a2;
        *(float4*)&outbuf[w][3][c4 * 4] = a3;
    }
    __syncthreads();

    // ---- cross-wave reduce + store partial: idx = h*128 + c, 2 per thread
    #pragma unroll
    for (int k = 0; k < 2; ++k) {
        int idx = t + 256 * k;
        int h = idx >> 7;
        int c = idx & 127;
        float sv = outbuf[0][h][c] + outbuf[1][h][c] + outbuf[2][h][c] + outbuf[3][h][c];
        partial[((size_t)e * NB * NN + (size_t)b * NN + r) * 512 + idx] = sv;
    }
}

// Kernel 2: out = partial[e=0] + partial[e=1]  (524288 floats)
__global__ __launch_bounds__(256)
void edge_attn_combine(const float* __restrict__ partial, float* __restrict__ out) {
    int i = blockIdx.x * 256 + threadIdx.x;   // float4 index, 131072 total
    float4 p0 = *(const float4*)(partial + (size_t)i * 4);
    float4 p1 = *(const float4*)(partial + 524288 + (size_t)i * 4);
    float4 o; o.x = p0.x + p1.x; o.y = p0.y + p1.y; o.z = p0.z + p1.z; o.w = p0.w + p1.w;
    *(float4*)(out + (size_t)i * 4) = o;
}

extern "C" void kernel_launch(void* const* d_in, const int* in_sizes, int n_in,
                              void* d_out, int out_size, void* d_ws, size_t ws_size,
                              hipStream_t stream) {
    const float* edge_msgs   = (const float*)d_in[0];
    const float* node_states = (const float*)d_in[1];
    const float* W           = (const float*)d_in[2];
    const float* bvec        = (const float*)d_in[3];
    const int*   edges       = (const int*)d_in[4];
    float* out     = (float*)d_out;
    float* partial = (float*)d_ws;   // [2][8][128][4][128] floats = 4 MB

    edge_attn_partial<<<dim3(NB * NN * 2), dim3(256), 0, stream>>>(
        edge_msgs, node_states, W, bvec, edges, partial);
    edge_attn_combine<<<dim3(131072 / 256), dim3(256), 0, stream>>>(partial, out);
}